// Round 10
// baseline (136.488 us; speedup 1.0000x reference)
//
#include <hip/hip_runtime.h>
#include <hip/hip_bf16.h>

typedef __bf16 bf16;
typedef bf16 bf16x8 __attribute__((ext_vector_type(8)));
typedef float floatx4 __attribute__((ext_vector_type(4)));

#define GLOBAL_AS __attribute__((address_space(1)))
#define LDS_AS __attribute__((address_space(3)))

// ---------------------------------------------------------------------------
// GEMM: C[m][n] = sum_k A[m][k] * W[n][k]  (+ bias[n] if bias != null)
// Compile-time shapes. 128x128 tile, BK=32, 4 waves, 4x4 16x16x32 bf16 MFMA,
// f32 accumulate. __launch_bounds__(256,2) -> >=2 blocks/CU.
// f32 operands: cvt-in-staging (R6-proven, faster than separate cvt pass).
// bf16 operands: async global_load_lds(16B) staging (m97 structure).
// ---------------------------------------------------------------------------
template<typename CT, bool AF32, bool WF32, int M, int N, int K, int LDA, int LDC>
__global__ __launch_bounds__(256, 2)
void gemm_bt(const void* __restrict__ Av, const void* __restrict__ Wv,
             CT* __restrict__ C, const float* __restrict__ bias)
{
    __shared__ __align__(16) bf16 As[128 * 32];
    __shared__ __align__(16) bf16 Bs[128 * 32];

    const int tid  = threadIdx.x;
    const int lane = tid & 63;
    const int wave = tid >> 6;
    const int row0 = blockIdx.x * 128;
    const int col0 = blockIdx.y * 128;

    const int wm = (wave & 1) * 64;
    const int wn = (wave >> 1) * 64;

    floatx4 acc[4][4] = {};

    const int fr = lane & 15;
    const int fk = (lane >> 4) * 8;

    const int lr = lane >> 2;        // async staging: row within 16-row chunk
    const int lk = (lane & 3) * 8;   //                k offset within row

    for (int k0 = 0; k0 < K; k0 += 32) {
        // ---- A staging ----
        if (AF32) {
            #pragma unroll
            for (int c = 0; c < 2; ++c) {
                const int idx = tid + c * 256;   // 0..511
                const int r   = idx >> 2;
                const int cb  = (idx & 3) * 8;
                const float4* g = (const float4*)((const float*)Av
                                   + (size_t)(row0 + r) * LDA + k0 + cb);
                float4 g0 = g[0], g1 = g[1];
                bf16x8 va;
                va[0]=(bf16)g0.x; va[1]=(bf16)g0.y; va[2]=(bf16)g0.z; va[3]=(bf16)g0.w;
                va[4]=(bf16)g1.x; va[5]=(bf16)g1.y; va[6]=(bf16)g1.z; va[7]=(bf16)g1.w;
                *(bf16x8*)(As + r * 32 + cb) = va;
            }
        } else {
            #pragma unroll
            for (int c = 0; c < 2; ++c) {
                const int chunk = wave * 2 + c;
                const int r = chunk * 16 + lr;
                const bf16* gA = (const bf16*)Av + (size_t)(row0 + r) * LDA + k0 + lk;
                __builtin_amdgcn_global_load_lds((const GLOBAL_AS void*)gA,
                                                 (LDS_AS void*)(As + chunk * 512),
                                                 16, 0, 0);
            }
        }
        // ---- W staging ----
        if (WF32) {
            #pragma unroll
            for (int c = 0; c < 2; ++c) {
                const int idx = tid + c * 256;
                const int r   = idx >> 2;
                const int cb  = (idx & 3) * 8;
                const float4* g = (const float4*)((const float*)Wv
                                   + (size_t)(col0 + r) * K + k0 + cb);
                float4 g0 = g[0], g1 = g[1];
                bf16x8 vw;
                vw[0]=(bf16)g0.x; vw[1]=(bf16)g0.y; vw[2]=(bf16)g0.z; vw[3]=(bf16)g0.w;
                vw[4]=(bf16)g1.x; vw[5]=(bf16)g1.y; vw[6]=(bf16)g1.z; vw[7]=(bf16)g1.w;
                *(bf16x8*)(Bs + r * 32 + cb) = vw;
            }
        } else {
            #pragma unroll
            for (int c = 0; c < 2; ++c) {
                const int chunk = wave * 2 + c;
                const int r = chunk * 16 + lr;
                const bf16* gB = (const bf16*)Wv + (size_t)(col0 + r) * K + k0 + lk;
                __builtin_amdgcn_global_load_lds((const GLOBAL_AS void*)gB,
                                                 (LDS_AS void*)(Bs + chunk * 512),
                                                 16, 0, 0);
            }
        }
        __syncthreads();

        bf16x8 af[4], bfr[4];
        #pragma unroll
        for (int i = 0; i < 4; ++i) {
            af[i]  = *(const bf16x8*)(As + (wm + i * 16 + fr) * 32 + fk);
            bfr[i] = *(const bf16x8*)(Bs + (wn + i * 16 + fr) * 32 + fk);
        }
        #pragma unroll
        for (int i = 0; i < 4; ++i)
            #pragma unroll
            for (int j = 0; j < 4; ++j)
                acc[i][j] = __builtin_amdgcn_mfma_f32_16x16x32_bf16(
                    af[i], bfr[j], acc[i][j], 0, 0, 0);

        __syncthreads();
    }

    const int fc  = lane & 15;
    const int fr4 = (lane >> 4) * 4;
    #pragma unroll
    for (int i = 0; i < 4; ++i) {
        #pragma unroll
        for (int j = 0; j < 4; ++j) {
            const int col = col0 + wn + j * 16 + fc;
            const float b = bias ? bias[col] : 0.0f;
            #pragma unroll
            for (int r = 0; r < 4; ++r) {
                const int row = row0 + wm + i * 16 + fr4 + r;
                C[(size_t)row * LDC + col] = (CT)(acc[i][j][r] + b);
            }
        }
    }
}

// ---------------------------------------------------------------------------
// MFMA local-window attention (R7/R8-verified core). One wave per
// (b, h, 16-row i-tile); reads qkv [B*N][2304], writes DENSE out [B*N][768].
// ---------------------------------------------------------------------------
__global__ __launch_bounds__(256)
void attn_tile(const bf16* __restrict__ qkv, bf16* __restrict__ aout)
{
    __shared__ __align__(16) bf16 Ks[4][32][72];
    __shared__ __align__(16) bf16 Vt[4][64][40];
    __shared__ __align__(16) bf16 Ps[4][16][40];

    const int w    = threadIdx.x >> 6;
    const int lane = threadIdx.x & 63;
    const int c    = lane & 15;
    const int q    = lane >> 4;
    const int wid  = blockIdx.x * 4 + w;   // 0..3071
    const int it   = wid & 127;
    const int bh   = wid >> 7;             // 0..23
    const int h    = bh % 12;
    const int b    = bh / 12;
    const int I0   = it * 16;
    const int bbase = b * 2048;
    const int j0   = I0 - 7;

    #pragma unroll
    for (int itr = 0; itr < 4; ++itr) {
        int idx = itr * 64 + lane;        // 0..255
        int row = idx >> 3;               // 0..31
        int dc  = (idx & 7) * 8;          // 0,8,...,56
        int jc  = j0 + row; jc = jc < 0 ? 0 : (jc > 2047 ? 2047 : jc);
        const bf16* base = qkv + (size_t)(bbase + jc) * 2304 + h * 64 + dc;
        bf16x8 kv = *(const bf16x8*)(base + 768);
        bf16x8 vv = *(const bf16x8*)(base + 1536);
        *(bf16x8*)(&Ks[w][row][dc]) = kv;
        #pragma unroll
        for (int e = 0; e < 8; ++e) Vt[w][dc + e][row] = vv[e];
    }

    const bf16* qrow = qkv + (size_t)(bbase + I0 + c) * 2304 + h * 64;
    bf16x8 aq0 = *(const bf16x8*)(qrow + q * 8);
    bf16x8 aq1 = *(const bf16x8*)(qrow + 32 + q * 8);

    __syncthreads();

    floatx4 st[2] = {};
    #pragma unroll
    for (int t = 0; t < 2; ++t) {
        bf16x8 k0 = *(const bf16x8*)(&Ks[w][t * 16 + c][q * 8]);
        bf16x8 k1 = *(const bf16x8*)(&Ks[w][t * 16 + c][32 + q * 8]);
        st[t] = __builtin_amdgcn_mfma_f32_16x16x32_bf16(aq0, k0, st[t], 0, 0, 0);
        st[t] = __builtin_amdgcn_mfma_f32_16x16x32_bf16(aq1, k1, st[t], 0, 0, 0);
    }

    float s[2][4];
    #pragma unroll
    for (int t = 0; t < 2; ++t)
        #pragma unroll
        for (int r = 0; r < 4; ++r) {
            int il = q * 4 + r;
            int jl = t * 16 + c;
            int ja = j0 + jl;
            bool valid = (jl >= il) && (jl <= il + 14) && (ja >= 0) && (ja < 2048);
            s[t][r] = valid ? st[t][r] * 0.125f : -1e30f;
        }

    float l[4], p[2][4];
    #pragma unroll
    for (int r = 0; r < 4; ++r) {
        float m2 = fmaxf(s[0][r], s[1][r]);
        #pragma unroll
        for (int mk = 1; mk < 16; mk <<= 1) m2 = fmaxf(m2, __shfl_xor(m2, mk, 64));
        p[0][r] = __expf(s[0][r] - m2);
        p[1][r] = __expf(s[1][r] - m2);
        float l2 = p[0][r] + p[1][r];
        #pragma unroll
        for (int mk = 1; mk < 16; mk <<= 1) l2 += __shfl_xor(l2, mk, 64);
        l[r] = l2;
    }

    #pragma unroll
    for (int r = 0; r < 4; ++r) {
        Ps[w][q * 4 + r][c]      = (bf16)p[0][r];
        Ps[w][q * 4 + r][16 + c] = (bf16)p[1][r];
    }
    __syncthreads();

    bf16x8 ap = *(const bf16x8*)(&Ps[w][c][q * 8]);
    floatx4 ov[4];
    #pragma unroll
    for (int nt = 0; nt < 4; ++nt) {
        bf16x8 vf = *(const bf16x8*)(&Vt[w][nt * 16 + c][q * 8]);
        floatx4 z = {};
        ov[nt] = __builtin_amdgcn_mfma_f32_16x16x32_bf16(ap, vf, z, 0, 0, 0);
    }

    float rl[4];
    #pragma unroll
    for (int r = 0; r < 4; ++r) rl[r] = 1.0f / l[r];
    #pragma unroll
    for (int r = 0; r < 4; ++r) {
        bf16* orow = aout + (size_t)(bbase + I0 + q * 4 + r) * 768 + h * 64;
        #pragma unroll
        for (int nt = 0; nt < 4; ++nt)
            orow[nt * 16 + c] = (bf16)(ov[nt][r] * rl[r]);
    }
}

// ---------------------------------------------------------------------------
// In-place attention variant (R8-proven) for the small-ws fallback.
// ---------------------------------------------------------------------------
__global__ __launch_bounds__(256)
void attn_tile_ip(bf16* __restrict__ qkv)
{
    __shared__ __align__(16) bf16 Ks[4][32][72];
    __shared__ __align__(16) bf16 Vt[4][64][40];
    __shared__ __align__(16) bf16 Ps[4][16][40];

    const int w    = threadIdx.x >> 6;
    const int lane = threadIdx.x & 63;
    const int c    = lane & 15;
    const int q    = lane >> 4;
    const int wid  = blockIdx.x * 4 + w;
    const int it   = wid & 127;
    const int bh   = wid >> 7;
    const int h    = bh % 12;
    const int b    = bh / 12;
    const int I0   = it * 16;
    const int bbase = b * 2048;
    const int j0   = I0 - 7;

    #pragma unroll
    for (int itr = 0; itr < 4; ++itr) {
        int idx = itr * 64 + lane;
        int row = idx >> 3;
        int dc  = (idx & 7) * 8;
        int jc  = j0 + row; jc = jc < 0 ? 0 : (jc > 2047 ? 2047 : jc);
        const bf16* base = qkv + (size_t)(bbase + jc) * 2304 + h * 64 + dc;
        bf16x8 kv = *(const bf16x8*)(base + 768);
        bf16x8 vv = *(const bf16x8*)(base + 1536);
        *(bf16x8*)(&Ks[w][row][dc]) = kv;
        #pragma unroll
        for (int e = 0; e < 8; ++e) Vt[w][dc + e][row] = vv[e];
    }

    const bf16* qrow = qkv + (size_t)(bbase + I0 + c) * 2304 + h * 64;
    bf16x8 aq0 = *(const bf16x8*)(qrow + q * 8);
    bf16x8 aq1 = *(const bf16x8*)(qrow + 32 + q * 8);

    __syncthreads();

    floatx4 st[2] = {};
    #pragma unroll
    for (int t = 0; t < 2; ++t) {
        bf16x8 k0 = *(const bf16x8*)(&Ks[w][t * 16 + c][q * 8]);
        bf16x8 k1 = *(const bf16x8*)(&Ks[w][t * 16 + c][32 + q * 8]);
        st[t] = __builtin_amdgcn_mfma_f32_16x16x32_bf16(aq0, k0, st[t], 0, 0, 0);
        st[t] = __builtin_amdgcn_mfma_f32_16x16x32_bf16(aq1, k1, st[t], 0, 0, 0);
    }

    float s[2][4];
    #pragma unroll
    for (int t = 0; t < 2; ++t)
        #pragma unroll
        for (int r = 0; r < 4; ++r) {
            int il = q * 4 + r;
            int jl = t * 16 + c;
            int ja = j0 + jl;
            bool valid = (jl >= il) && (jl <= il + 14) && (ja >= 0) && (ja < 2048);
            s[t][r] = valid ? st[t][r] * 0.125f : -1e30f;
        }

    float l[4], p[2][4];
    #pragma unroll
    for (int r = 0; r < 4; ++r) {
        float m2 = fmaxf(s[0][r], s[1][r]);
        #pragma unroll
        for (int mk = 1; mk < 16; mk <<= 1) m2 = fmaxf(m2, __shfl_xor(m2, mk, 64));
        p[0][r] = __expf(s[0][r] - m2);
        p[1][r] = __expf(s[1][r] - m2);
        float l2 = p[0][r] + p[1][r];
        #pragma unroll
        for (int mk = 1; mk < 16; mk <<= 1) l2 += __shfl_xor(l2, mk, 64);
        l[r] = l2;
    }

    #pragma unroll
    for (int r = 0; r < 4; ++r) {
        Ps[w][q * 4 + r][c]      = (bf16)p[0][r];
        Ps[w][q * 4 + r][16 + c] = (bf16)p[1][r];
    }
    __syncthreads();

    bf16x8 ap = *(const bf16x8*)(&Ps[w][c][q * 8]);
    floatx4 ov[4];
    #pragma unroll
    for (int nt = 0; nt < 4; ++nt) {
        bf16x8 vf = *(const bf16x8*)(&Vt[w][nt * 16 + c][q * 8]);
        floatx4 z = {};
        ov[nt] = __builtin_amdgcn_mfma_f32_16x16x32_bf16(ap, vf, z, 0, 0, 0);
    }

    float rl[4];
    #pragma unroll
    for (int r = 0; r < 4; ++r) rl[r] = 1.0f / l[r];
    #pragma unroll
    for (int r = 0; r < 4; ++r) {
        bf16* orow = (bf16*)qkv + (size_t)(bbase + I0 + q * 4 + r) * 2304 + h * 64;
        #pragma unroll
        for (int nt = 0; nt < 4; ++nt)
            orow[nt * 16 + c] = (bf16)(ov[nt][r] * rl[r]);
    }
}

// ---------------------------------------------------------------------------
extern "C" void kernel_launch(void* const* d_in, const int* in_sizes, int n_in,
                              void* d_out, int out_size, void* d_ws, size_t ws_size,
                              hipStream_t stream)
{
    const float* x      = (const float*)d_in[0];  // [4096][768] f32
    const float* w_qkv  = (const float*)d_in[1];  // [2304][768] f32
    const float* w_proj = (const float*)d_in[2];  // [768][768]  f32
    const float* b_proj = (const float*)d_in[3];  // [768]       f32
    float* out = (float*)d_out;                   // [4096][768] f32

    bf16* qkv = (bf16*)d_ws;                      // [4096][2304] bf16, 18.87 MB
    const size_t QKV_B = (size_t)4096 * 2304 * 2;
    const size_t AO_B  = (size_t)4096 * 768 * 2;  // dense attn out, 6.29 MB

    // 1) qkv = bf16(x) @ bf16(w_qkv)^T  — f32-direct staging (saves cvt pass)
    gemm_bt<bf16, true, true, 4096, 2304, 768, 768, 2304>
        <<<dim3(32, 18), 256, 0, stream>>>(x, w_qkv, qkv, nullptr);

    if (ws_size >= QKV_B + AO_B) {
        bf16* aout = (bf16*)((char*)d_ws + QKV_B);

        // 2) attention -> dense [4096][768]
        attn_tile<<<dim3(768), 256, 0, stream>>>(qkv, aout);

        // 3) out = aout @ bf16(w_proj)^T + b_proj  (contiguous A, lda=768)
        gemm_bt<float, false, true, 4096, 768, 768, 768, 768>
            <<<dim3(32, 6), 256, 0, stream>>>(aout, w_proj, out, b_proj);
    } else {
        // fallback: in-place attention into q slots, strided A
        attn_tile_ip<<<dim3(768), 256, 0, stream>>>(qkv);
        gemm_bt<float, false, true, 4096, 768, 768, 2304, 768>
            <<<dim3(32, 6), 256, 0, stream>>>(qkv, w_proj, out, b_proj);
    }
}

// Round 11
// 122.857 us; speedup vs baseline: 1.1110x; 1.1110x over previous
//
#include <hip/hip_runtime.h>
#include <hip/hip_bf16.h>

typedef __bf16 bf16;
typedef bf16 bf16x4 __attribute__((ext_vector_type(4)));
typedef bf16 bf16x8 __attribute__((ext_vector_type(8)));
typedef float floatx4 __attribute__((ext_vector_type(4)));

#define GLOBAL_AS __attribute__((address_space(1)))
#define LDS_AS __attribute__((address_space(3)))

// ---------------------------------------------------------------------------
// f32 -> bf16 conversion for x, w_qkv, w_proj (float4 granular).
// R9/R10 A/B test: cvt3 + bf16-async GEMM1 beats f32-direct GEMM1 by ~10 us.
// ---------------------------------------------------------------------------
__global__ __launch_bounds__(256)
void cvt3_f32_bf16(const float* __restrict__ s0, const float* __restrict__ s1,
                   const float* __restrict__ s2, bf16* __restrict__ d0,
                   bf16* __restrict__ d1, bf16* __restrict__ d2,
                   int n0, int n1, int n2)
{
    int t = blockIdx.x * blockDim.x + threadIdx.x;
    const float* s; bf16* d; int i;
    if (t < n0)                { s = s0; d = d0; i = t; }
    else if (t < n0 + n1)      { s = s1; d = d1; i = t - n0; }
    else if (t < n0 + n1 + n2) { s = s2; d = d2; i = t - n0 - n1; }
    else return;
    float4 v = ((const float4*)s)[i];
    bf16x4 o = { (bf16)v.x, (bf16)v.y, (bf16)v.z, (bf16)v.w };
    ((bf16x4*)d)[i] = o;
}

// ---------------------------------------------------------------------------
// GEMM: C[m][n] = sum_k A[m][k] * W[n][k]  (+ bias[n] if bias != null)
// Compile-time shapes. Tile TM x 128, BK=32, 256 thr (4 waves):
//   TM=128: waves 2x2 over 64x64 sub-tiles, 4x4 accs (GEMM1 geometry)
//   TM=64 : waves 2x2 over 32x64 sub-tiles, 2x4 accs (GEMM2: 2x the blocks,
//           fixes 192-block underoccupancy seen in R10 profile)
// bf16 operands: async global_load_lds(16B); f32 operands: cvt-in-staging.
// ---------------------------------------------------------------------------
template<typename CT, bool AF32, bool WF32, int TM, int M, int N, int K,
         int LDA, int LDC>
__global__ __launch_bounds__(256, 2)
void gemm_bt(const void* __restrict__ Av, const void* __restrict__ Wv,
             CT* __restrict__ C, const float* __restrict__ bias)
{
    constexpr int MI = TM / 32;          // acc rows per wave (4 or 2)
    __shared__ __align__(16) bf16 As[TM * 32];
    __shared__ __align__(16) bf16 Bs[128 * 32];

    const int tid  = threadIdx.x;
    const int lane = tid & 63;
    const int wave = tid >> 6;
    const int row0 = blockIdx.x * TM;
    const int col0 = blockIdx.y * 128;

    const int wm = (wave & 1) * (TM / 2);
    const int wn = (wave >> 1) * 64;

    floatx4 acc[MI][4] = {};

    const int fr = lane & 15;
    const int fk = (lane >> 4) * 8;

    const int lr = lane >> 2;        // async staging: row within 16-row chunk
    const int lk = (lane & 3) * 8;   //                k offset within row

    for (int k0 = 0; k0 < K; k0 += 32) {
        // ---- A staging ----
        if (AF32) {
            constexpr int NV = TM * 4;             // # of 8-elem vectors
            #pragma unroll
            for (int c = 0; c < NV / 256; ++c) {
                const int idx = tid + c * 256;
                const int r   = idx >> 2;
                const int cb  = (idx & 3) * 8;
                const float4* g = (const float4*)((const float*)Av
                                   + (size_t)(row0 + r) * LDA + k0 + cb);
                float4 g0 = g[0], g1 = g[1];
                bf16x8 va;
                va[0]=(bf16)g0.x; va[1]=(bf16)g0.y; va[2]=(bf16)g0.z; va[3]=(bf16)g0.w;
                va[4]=(bf16)g1.x; va[5]=(bf16)g1.y; va[6]=(bf16)g1.z; va[7]=(bf16)g1.w;
                *(bf16x8*)(As + r * 32 + cb) = va;
            }
        } else {
            constexpr int CAW = TM / 64;           // A chunks per wave
            #pragma unroll
            for (int c = 0; c < CAW; ++c) {
                const int chunk = wave * CAW + c;
                const int r = chunk * 16 + lr;
                const bf16* gA = (const bf16*)Av + (size_t)(row0 + r) * LDA + k0 + lk;
                __builtin_amdgcn_global_load_lds((const GLOBAL_AS void*)gA,
                                                 (LDS_AS void*)(As + chunk * 512),
                                                 16, 0, 0);
            }
        }
        // ---- W staging (always 128x32 tile = 8 chunks, 2 per wave) ----
        if (WF32) {
            #pragma unroll
            for (int c = 0; c < 2; ++c) {
                const int idx = tid + c * 256;
                const int r   = idx >> 2;
                const int cb  = (idx & 3) * 8;
                const float4* g = (const float4*)((const float*)Wv
                                   + (size_t)(col0 + r) * K + k0 + cb);
                float4 g0 = g[0], g1 = g[1];
                bf16x8 vw;
                vw[0]=(bf16)g0.x; vw[1]=(bf16)g0.y; vw[2]=(bf16)g0.z; vw[3]=(bf16)g0.w;
                vw[4]=(bf16)g1.x; vw[5]=(bf16)g1.y; vw[6]=(bf16)g1.z; vw[7]=(bf16)g1.w;
                *(bf16x8*)(Bs + r * 32 + cb) = vw;
            }
        } else {
            #pragma unroll
            for (int c = 0; c < 2; ++c) {
                const int chunk = wave * 2 + c;
                const int r = chunk * 16 + lr;
                const bf16* gB = (const bf16*)Wv + (size_t)(col0 + r) * K + k0 + lk;
                __builtin_amdgcn_global_load_lds((const GLOBAL_AS void*)gB,
                                                 (LDS_AS void*)(Bs + chunk * 512),
                                                 16, 0, 0);
            }
        }
        __syncthreads();

        bf16x8 af[MI], bfr[4];
        #pragma unroll
        for (int i = 0; i < MI; ++i)
            af[i]  = *(const bf16x8*)(As + (wm + i * 16 + fr) * 32 + fk);
        #pragma unroll
        for (int j = 0; j < 4; ++j)
            bfr[j] = *(const bf16x8*)(Bs + (wn + j * 16 + fr) * 32 + fk);
        #pragma unroll
        for (int i = 0; i < MI; ++i)
            #pragma unroll
            for (int j = 0; j < 4; ++j)
                acc[i][j] = __builtin_amdgcn_mfma_f32_16x16x32_bf16(
                    af[i], bfr[j], acc[i][j], 0, 0, 0);

        __syncthreads();
    }

    const int fc  = lane & 15;
    const int fr4 = (lane >> 4) * 4;
    #pragma unroll
    for (int i = 0; i < MI; ++i) {
        #pragma unroll
        for (int j = 0; j < 4; ++j) {
            const int col = col0 + wn + j * 16 + fc;
            const float b = bias ? bias[col] : 0.0f;
            #pragma unroll
            for (int r = 0; r < 4; ++r) {
                const int row = row0 + wm + i * 16 + fr4 + r;
                C[(size_t)row * LDC + col] = (CT)(acc[i][j][r] + b);
            }
        }
    }
}

// ---------------------------------------------------------------------------
// MFMA local-window attention (R7-R10 verified). One wave per
// (b, h, 16-row i-tile); reads qkv [B*N][2304], writes dense out [B*N][768].
// ---------------------------------------------------------------------------
__global__ __launch_bounds__(256)
void attn_tile(const bf16* __restrict__ qkv, bf16* __restrict__ aout)
{
    __shared__ __align__(16) bf16 Ks[4][32][72];
    __shared__ __align__(16) bf16 Vt[4][64][40];
    __shared__ __align__(16) bf16 Ps[4][16][40];

    const int w    = threadIdx.x >> 6;
    const int lane = threadIdx.x & 63;
    const int c    = lane & 15;
    const int q    = lane >> 4;
    const int wid  = blockIdx.x * 4 + w;   // 0..3071
    const int it   = wid & 127;
    const int bh   = wid >> 7;             // 0..23
    const int h    = bh % 12;
    const int b    = bh / 12;
    const int I0   = it * 16;
    const int bbase = b * 2048;
    const int j0   = I0 - 7;

    #pragma unroll
    for (int itr = 0; itr < 4; ++itr) {
        int idx = itr * 64 + lane;        // 0..255
        int row = idx >> 3;               // 0..31
        int dc  = (idx & 7) * 8;          // 0,8,...,56
        int jc  = j0 + row; jc = jc < 0 ? 0 : (jc > 2047 ? 2047 : jc);
        const bf16* base = qkv + (size_t)(bbase + jc) * 2304 + h * 64 + dc;
        bf16x8 kv = *(const bf16x8*)(base + 768);
        bf16x8 vv = *(const bf16x8*)(base + 1536);
        *(bf16x8*)(&Ks[w][row][dc]) = kv;
        #pragma unroll
        for (int e = 0; e < 8; ++e) Vt[w][dc + e][row] = vv[e];
    }

    const bf16* qrow = qkv + (size_t)(bbase + I0 + c) * 2304 + h * 64;
    bf16x8 aq0 = *(const bf16x8*)(qrow + q * 8);
    bf16x8 aq1 = *(const bf16x8*)(qrow + 32 + q * 8);

    __syncthreads();

    floatx4 st[2] = {};
    #pragma unroll
    for (int t = 0; t < 2; ++t) {
        bf16x8 k0 = *(const bf16x8*)(&Ks[w][t * 16 + c][q * 8]);
        bf16x8 k1 = *(const bf16x8*)(&Ks[w][t * 16 + c][32 + q * 8]);
        st[t] = __builtin_amdgcn_mfma_f32_16x16x32_bf16(aq0, k0, st[t], 0, 0, 0);
        st[t] = __builtin_amdgcn_mfma_f32_16x16x32_bf16(aq1, k1, st[t], 0, 0, 0);
    }

    float s[2][4];
    #pragma unroll
    for (int t = 0; t < 2; ++t)
        #pragma unroll
        for (int r = 0; r < 4; ++r) {
            int il = q * 4 + r;
            int jl = t * 16 + c;
            int ja = j0 + jl;
            bool valid = (jl >= il) && (jl <= il + 14) && (ja >= 0) && (ja < 2048);
            s[t][r] = valid ? st[t][r] * 0.125f : -1e30f;
        }

    float l[4], p[2][4];
    #pragma unroll
    for (int r = 0; r < 4; ++r) {
        float m2 = fmaxf(s[0][r], s[1][r]);
        #pragma unroll
        for (int mk = 1; mk < 16; mk <<= 1) m2 = fmaxf(m2, __shfl_xor(m2, mk, 64));
        p[0][r] = __expf(s[0][r] - m2);
        p[1][r] = __expf(s[1][r] - m2);
        float l2 = p[0][r] + p[1][r];
        #pragma unroll
        for (int mk = 1; mk < 16; mk <<= 1) l2 += __shfl_xor(l2, mk, 64);
        l[r] = l2;
    }

    #pragma unroll
    for (int r = 0; r < 4; ++r) {
        Ps[w][q * 4 + r][c]      = (bf16)p[0][r];
        Ps[w][q * 4 + r][16 + c] = (bf16)p[1][r];
    }
    __syncthreads();

    bf16x8 ap = *(const bf16x8*)(&Ps[w][c][q * 8]);
    floatx4 ov[4];
    #pragma unroll
    for (int nt = 0; nt < 4; ++nt) {
        bf16x8 vf = *(const bf16x8*)(&Vt[w][nt * 16 + c][q * 8]);
        floatx4 z = {};
        ov[nt] = __builtin_amdgcn_mfma_f32_16x16x32_bf16(ap, vf, z, 0, 0, 0);
    }

    float rl[4];
    #pragma unroll
    for (int r = 0; r < 4; ++r) rl[r] = 1.0f / l[r];
    #pragma unroll
    for (int r = 0; r < 4; ++r) {
        bf16* orow = aout + (size_t)(bbase + I0 + q * 4 + r) * 768 + h * 64;
        #pragma unroll
        for (int nt = 0; nt < 4; ++nt)
            orow[nt * 16 + c] = (bf16)(ov[nt][r] * rl[r]);
    }
}

// ---------------------------------------------------------------------------
extern "C" void kernel_launch(void* const* d_in, const int* in_sizes, int n_in,
                              void* d_out, int out_size, void* d_ws, size_t ws_size,
                              hipStream_t stream)
{
    const float* x      = (const float*)d_in[0];  // [4096][768] f32
    const float* w_qkv  = (const float*)d_in[1];  // [2304][768] f32
    const float* w_proj = (const float*)d_in[2];  // [768][768]  f32
    const float* b_proj = (const float*)d_in[3];  // [768]       f32
    float* out = (float*)d_out;                   // [4096][768] f32

    bf16* qkv = (bf16*)d_ws;                      // [4096][2304] bf16, 18.87 MB
    const size_t QKV_B  = (size_t)4096 * 2304 * 2;
    const size_t AO_B   = (size_t)4096 * 768 * 2; // 6.29 MB
    const size_t XB_B   = (size_t)4096 * 768 * 2;
    const size_t WQKV_B = (size_t)2304 * 768 * 2;
    const size_t WPRJ_B = (size_t)768 * 768 * 2;

    if (ws_size >= QKV_B + AO_B + XB_B + WQKV_B + WPRJ_B) {
        // main path (R9 config + TM=64 GEMM2)
        bf16* aout = (bf16*)((char*)d_ws + QKV_B);
        bf16* xb   = (bf16*)((char*)aout + AO_B);
        bf16* wqb  = (bf16*)((char*)xb + XB_B);
        bf16* wpb  = (bf16*)((char*)wqb + WQKV_B);

        const int n0 = 4096 * 768 / 4, n1 = 2304 * 768 / 4, n2 = 768 * 768 / 4;
        cvt3_f32_bf16<<<dim3((n0 + n1 + n2) / 256), 256, 0, stream>>>(
            x, w_qkv, w_proj, xb, wqb, wpb, n0, n1, n2);

        // 1) qkv = xb @ wqb^T   (TM=128, grid 576 blocks)
        gemm_bt<bf16, false, false, 128, 4096, 2304, 768, 768, 2304>
            <<<dim3(32, 18), 256, 0, stream>>>(xb, wqb, qkv, nullptr);

        // 2) attention -> dense [4096][768]
        attn_tile<<<dim3(768), 256, 0, stream>>>(qkv, aout);

        // 3) out = aout @ wpb^T + b_proj   (TM=64, grid 384 blocks)
        gemm_bt<float, false, false, 64, 4096, 768, 768, 768, 768>
            <<<dim3(64, 6), 256, 0, stream>>>(aout, wpb, out, b_proj);
    } else {
        // fallback: f32 cvt inside GEMM staging (R6-proven), minimal ws
        gemm_bt<bf16, true, true, 128, 4096, 2304, 768, 768, 2304>
            <<<dim3(32, 18), 256, 0, stream>>>(x, w_qkv, qkv, nullptr);

        bf16* aout = (bf16*)((char*)d_ws + QKV_B);
        attn_tile<<<dim3(768), 256, 0, stream>>>(qkv, aout);

        gemm_bt<float, false, true, 64, 4096, 768, 768, 768, 768>
            <<<dim3(64, 6), 256, 0, stream>>>(aout, w_proj, out, b_proj);
    }
}